// Round 11
// baseline (531.988 us; speedup 1.0000x reference)
//
#include <hip/hip_runtime.h>
#include <hip/hip_fp16.h>

#define NN 100000
#define NE 1600000
#define DD 128
#define CAP 48           // bucket capacity; max in-degree ~40
#define FRAG_ELEMS 16384 // one 128x128 matrix in fragment order

#define NRNG 8           // dst ranges == XCD count
#define RNODES 12500     // NN / NRNG
#define EPT 8            // edges per thread in fill
#define FILL_T (NE / EPT)                 // 200000 threads per range pass
#define FILL_BPR ((FILL_T + 255) / 256)   // 782 blocks per range
#define FILL_B (NRNG * FILL_BPR)          // 6256 fill blocks (placed FIRST: rng = b&7)
#define XCAST_B ((NN * DD / 8) / 256)     // 6250 xcast blocks
#define PREP_B (FILL_B + XCAST_B + 384)   // + 384 wprep blocks = 12890

typedef __attribute__((ext_vector_type(8))) _Float16 half8;
typedef __attribute__((ext_vector_type(4))) float f32x4;

// ---------------- fused prep: fill | xcast | wprep in one dispatch ----------------
// The three are mutually independent; xcast (~13us) and wprep (~5us) hide under
// fill's ~74us. Fill blocks first so rng = blockIdx&7 keeps the exact XCD
// mapping (round-robin dispatch) proven in r3. cnt zeroed by memset beforehand.
__global__ __launch_bounds__(256) void k_prep(
    const int* __restrict__ src, const int* __restrict__ dst,
    int* __restrict__ cnt, int* __restrict__ bkt,
    const float* __restrict__ x, _Float16* __restrict__ xh,
    const float* __restrict__ W0, const float* __restrict__ W1,
    const float* __restrict__ W2, const float* __restrict__ W3,
    const float* __restrict__ W4, const float* __restrict__ W5,
    _Float16* __restrict__ wfrag) {

    int b = blockIdx.x;
    int tid = threadIdx.x;

    if (b < FILL_B) {
        // ---- bucket fill (r3 config, best measured 73.9us over 5 variants) ----
        int rng = b & (NRNG - 1);
        int t = (b >> 3) * 256 + tid;
        if (t >= FILL_T) return;
        int lo = rng * RNODES;
        const int4* d4 = (const int4*)dst;
        const int4* s4 = (const int4*)src;
        int4 d0 = d4[t * 2];
        int4 d1 = d4[t * 2 + 1];
        int4 s0 = s4[t * 2];
        int4 s1 = s4[t * 2 + 1];
        int dd[8] = { d0.x, d0.y, d0.z, d0.w, d1.x, d1.y, d1.z, d1.w };
        int ss[8] = { s0.x, s0.y, s0.z, s0.w, s1.x, s1.y, s1.z, s1.w };
#pragma unroll
        for (int k = 0; k < 8; ++k) {
            int d = dd[k];
            unsigned rel = (unsigned)(d - lo);
            if (rel < (unsigned)RNODES) {
                int p = atomicAdd(&cnt[d], 1);
                if (p < CAP) bkt[(size_t)d * CAP + p] = ss[k];
            }
        }
    } else if (b < FILL_B + XCAST_B) {
        // ---- cast x fp32 -> f16 ----
        int t = (b - FILL_B) * 256 + tid;
        const float* p = x + (size_t)t * 8;
        float4 v0 = *(const float4*)p;
        float4 v1 = *(const float4*)(p + 4);
        half8 o = { (_Float16)v0.x, (_Float16)v0.y, (_Float16)v0.z, (_Float16)v0.w,
                    (_Float16)v1.x, (_Float16)v1.y, (_Float16)v1.z, (_Float16)v1.w };
        *(half8*)(xh + (size_t)t * 8) = o;
    } else {
        // ---- weight prep: transpose + f16 hi/lo split into MFMA B-frag order ----
        int wb = b - FILL_B - XCAST_B;               // 0..383
        int mat = wb >> 6;
        int e = (wb & 63) * 256 + tid;               // 0..16383
        const float* W = (mat == 0) ? W0 : (mat == 1) ? W1 : (mat == 2) ? W2
                       : (mat == 3) ? W3 : (mat == 4) ? W4 : W5;
        int j = e & 7;
        int lane = (e >> 3) & 63;
        int ct = (e >> 9) & 7;
        int kt = e >> 12;
        int k = kt * 32 + (lane >> 4) * 8 + j;
        int n = ct * 16 + (lane & 15);
        float v = W[k * 128 + n];
        _Float16 hi = (_Float16)v;
        _Float16 lo = (_Float16)(v - (float)hi);
        _Float16* mb = wfrag + (size_t)mat * 2 * FRAG_ELEMS;
        mb[e] = hi;
        mb[FRAG_ELEMS + e] = lo;
    }
}

// ---------------- fused layer: aggregate (into LDS) + transform ----------------
// Phase A: each wave aggregates its 16 nodes' mean rows into smean (XOR-swizzled
// 16B chunks: unswizzled [64][128]f16 A-frag reads are a 16-way bank conflict,
// all m16 rows land on the same bank group). Phase B: r9's LDS-staged MFMA loop
// with register-prefetched weights; mean A-frags come from smean instead of
// global. Eliminates the 51.2 MB/layer mean round-trip + one launch per layer.
// Weight chunk0 + self-term A prefetches issue BEFORE phase A (latency fully
// hidden under the gather).
__global__ __launch_bounds__(256) void k_layer(
    const _Float16* __restrict__ hin,
    const int* __restrict__ cnt, const int* __restrict__ bkt,
    const _Float16* __restrict__ wf,   // [WnHi|WnLo|WsHi|WsLo] x 16384
    const float* __restrict__ bias,
    _Float16* __restrict__ outh, float* __restrict__ outf) {

    __shared__ _Float16 smean[64 * 128];   // 16 KB, swizzled 16B chunks
    __shared__ _Float16 sw[2][4096];       // 16 KB hi/lo weight chunk

    int t = threadIdx.x;
    int wave = t >> 6;
    int lane = t & 63;
    int m16 = lane & 15;
    int kg = lane >> 4;
    int rowA = blockIdx.x * 64 + wave * 16 + m16;
    if (rowA >= NN) rowA = NN - 1;       // clamp (store is guarded)

    // early prefetch: weight chunk 0 + self-term A fragments (independent of phase A)
    half8 ph0, ph1, pl0, pl1;
    {
        const half8* gh = (const half8*)(wf);                 // s=0 hi, kt=0
        const half8* gl = (const half8*)(wf + FRAG_ELEMS);    // s=0 lo, kt=0
        ph0 = gh[t]; ph1 = gh[t + 256];
        pl0 = gl[t]; pl1 = gl[t + 256];
    }
    half8 afragS[4];
    {
        const _Float16* Ah = hin + (size_t)rowA * DD + kg * 8;
#pragma unroll
        for (int kt = 0; kt < 4; ++kt)
            afragS[kt] = *(const half8*)(Ah + kt * 32);
    }

    // ---- phase A: aggregate 16 nodes per wave into smean ----
    {
        int q = lane >> 4;
        int col = (lane & 15) * 8;
        for (int i = 0; i < 16; ++i) {
            int local = wave * 16 + i;
            int node = blockIdx.x * 64 + local;
            float a[8] = {};
            int deg = 0;
            if (node < NN) {                 // wave-uniform branch
                deg = cnt[node];
                int n = deg > CAP ? CAP : deg;
                const int* bb = bkt + (size_t)node * CAP;
                int e = 0;
                for (; e + 16 <= n; e += 16) {
                    int s0 = bb[e + q];
                    int s1 = bb[e + 4 + q];
                    int s2 = bb[e + 8 + q];
                    int s3 = bb[e + 12 + q];
                    half8 v0 = *(const half8*)(hin + (size_t)s0 * DD + col);
                    half8 v1 = *(const half8*)(hin + (size_t)s1 * DD + col);
                    half8 v2 = *(const half8*)(hin + (size_t)s2 * DD + col);
                    half8 v3 = *(const half8*)(hin + (size_t)s3 * DD + col);
#pragma unroll
                    for (int j = 0; j < 8; ++j)
                        a[j] += ((float)v0[j] + (float)v1[j]) + ((float)v2[j] + (float)v3[j]);
                }
                if (e + 8 <= n) {
                    int s0 = bb[e + q];
                    int s1 = bb[e + 4 + q];
                    half8 v0 = *(const half8*)(hin + (size_t)s0 * DD + col);
                    half8 v1 = *(const half8*)(hin + (size_t)s1 * DD + col);
#pragma unroll
                    for (int j = 0; j < 8; ++j) a[j] += (float)v0[j] + (float)v1[j];
                    e += 8;
                }
                if (e + 4 <= n) {
                    int s0 = bb[e + q];
                    half8 v0 = *(const half8*)(hin + (size_t)s0 * DD + col);
#pragma unroll
                    for (int j = 0; j < 8; ++j) a[j] += (float)v0[j];
                    e += 4;
                }
                if (e + q < n) {
                    int s0 = bb[e + q];
                    half8 v0 = *(const half8*)(hin + (size_t)s0 * DD + col);
#pragma unroll
                    for (int j = 0; j < 8; ++j) a[j] += (float)v0[j];
                }
            }
            // reduce the 4 quarters
#pragma unroll
            for (int j = 0; j < 8; ++j) {
                a[j] += __shfl_xor(a[j], 16);
                a[j] += __shfl_xor(a[j], 32);
            }
            if (q == 0) {
                float di = 1.0f / (float)(deg > 1 ? deg : 1);
                half8 o;
#pragma unroll
                for (int j = 0; j < 8; ++j) o[j] = (_Float16)(a[j] * di);
                int chunk = (lane & 15) ^ (local & 7);          // swizzled store
                *(half8*)(smean + local * 128 + chunk * 8) = o;
            }
        }
    }
    __syncthreads();

    // mean A-fragments from LDS (swizzle-matched)
    half8 afragM[4];
    {
        int localr = wave * 16 + m16;
#pragma unroll
        for (int kt = 0; kt < 4; ++kt) {
            int chunk = (kt * 4 + kg) ^ (localr & 7);
            afragM[kt] = *(const half8*)(smean + localr * 128 + chunk * 8);
        }
    }

    f32x4 acc[8] = {};

#pragma unroll
    for (int idx = 0; idx < 8; ++idx) {
        int s = idx >> 2;
        int kt = idx & 3;
        __syncthreads();           // previous chunk's LDS reads done
        {
            half8* dsth = (half8*)sw[0];
            half8* dstl = (half8*)sw[1];
            dsth[t]       = ph0;
            dsth[t + 256] = ph1;
            dstl[t]       = pl0;
            dstl[t + 256] = pl1;
        }
        if (idx < 7) {             // issue next chunk's loads; latency hides under MFMA
            int s2 = (idx + 1) >> 2;
            int kt2 = (idx + 1) & 3;
            const half8* gh = (const half8*)(wf + s2 * 2 * FRAG_ELEMS + kt2 * 4096);
            const half8* gl = (const half8*)(wf + s2 * 2 * FRAG_ELEMS + FRAG_ELEMS + kt2 * 4096);
            ph0 = gh[t]; ph1 = gh[t + 256];
            pl0 = gl[t]; pl1 = gl[t + 256];
        }
        __syncthreads();
        half8 a = s ? afragS[kt] : afragM[kt];
#pragma unroll
        for (int ct = 0; ct < 8; ++ct) {
            half8 bh = *(const half8*)(sw[0] + (ct * 64 + lane) * 8);
            half8 bl = *(const half8*)(sw[1] + (ct * 64 + lane) * 8);
            acc[ct] = __builtin_amdgcn_mfma_f32_16x16x32_f16(a, bh, acc[ct], 0, 0, 0);
            acc[ct] = __builtin_amdgcn_mfma_f32_16x16x32_f16(a, bl, acc[ct], 0, 0, 0);
        }
    }

    // epilogue: C layout col=lane&15, row=(lane>>4)*4+reg
    int rbase = blockIdx.x * 64 + wave * 16 + kg * 4;
    if (outh) {
#pragma unroll
        for (int ct = 0; ct < 8; ++ct) {
            int col = ct * 16 + m16;
            float bv = bias[col];
#pragma unroll
            for (int i = 0; i < 4; ++i) {
                int r = rbase + i;
                if (r < NN)
                    outh[(size_t)r * DD + col] = (_Float16)fmaxf(acc[ct][i] + bv, 0.0f);
            }
        }
    } else {
#pragma unroll
        for (int ct = 0; ct < 8; ++ct) {
            int col = ct * 16 + m16;
            float bv = bias[col];
#pragma unroll
            for (int i = 0; i < 4; ++i) {
                int r = rbase + i;
                if (r < NN)
                    outf[(size_t)r * DD + col] = acc[ct][i] + bv;
            }
        }
    }
}

// ---------------- fc (128->16) + log_softmax (fp32) ----------------
__global__ __launch_bounds__(256) void k_fc(const float* __restrict__ emb,
                                            const float* __restrict__ Wfc,
                                            const float* __restrict__ bfc,
                                            float* __restrict__ out) {
    __shared__ float se[16 * 128];
    __shared__ float swt[128 * 16];
    int t = threadIdx.x;
    int nb = blockIdx.x * 16;
    int idx = t * 8;
    *(float4*)(se + idx)      = *(const float4*)(emb + (size_t)nb * 128 + idx);
    *(float4*)(se + idx + 4)  = *(const float4*)(emb + (size_t)nb * 128 + idx + 4);
    *(float4*)(swt + idx)     = *(const float4*)(Wfc + idx);
    *(float4*)(swt + idx + 4) = *(const float4*)(Wfc + idx + 4);
    __syncthreads();

    int nl = t >> 4;
    int o = t & 15;
    float acc = bfc[o];
    const float* er = se + nl * 128;
#pragma unroll 8
    for (int k = 0; k < 128; ++k)
        acc += er[k] * swt[k * 16 + o];

    float m = acc;
#pragma unroll
    for (int d = 1; d < 16; d <<= 1) m = fmaxf(m, __shfl_xor(m, d, 16));
    float e = expf(acc - m);
    float ssum = e;
#pragma unroll
    for (int d = 1; d < 16; d <<= 1) ssum += __shfl_xor(ssum, d, 16);
    out[(size_t)(nb + nl) * 16 + o] = (acc - m) - logf(ssum);
}

extern "C" void kernel_launch(void* const* d_in, const int* in_sizes, int n_in,
                              void* d_out, int out_size, void* d_ws, size_t ws_size,
                              hipStream_t stream) {
    const float* x   = (const float*)d_in[0];
    const int*   ei  = (const int*)d_in[1];
    const float* Wn0 = (const float*)d_in[2];
    const float* Ws0 = (const float*)d_in[3];
    const float* b0  = (const float*)d_in[4];
    const float* Wn1 = (const float*)d_in[5];
    const float* Ws1 = (const float*)d_in[6];
    const float* b1  = (const float*)d_in[7];
    const float* Wn2 = (const float*)d_in[8];
    const float* Ws2 = (const float*)d_in[9];
    const float* b2  = (const float*)d_in[10];
    const float* Wfc = (const float*)d_in[11];
    const float* bfc = (const float*)d_in[12];

    const int* src = ei;
    const int* dst = ei + NE;

    float* emb_out = (float*)d_out;
    float* lsm_out = emb_out + (size_t)NN * 128;

    char* ws = (char*)d_ws;
    _Float16* xh    = (_Float16*)(ws);                   //  25,600,000 B
    _Float16* hA    = (_Float16*)(ws + 25600000);        //  25,600,000 B
    _Float16* hB    = (_Float16*)(ws + 51200000);        //  25,600,000 B
    int*      cnt   = (int*)     (ws + 102400000);       //     400,000 B
    int*      bkt   = (int*)     (ws + 102800000);       //  19,200,000 B (CAP=48)
    _Float16* wfrag = (_Float16*)(ws + 122000000);       //     393,216 B

    // ---- fused prep: memset cnt, then fill | xcast | wprep concurrently ----
    hipMemsetAsync(cnt, 0, NN * sizeof(int), stream);
    k_prep<<<PREP_B, 256, 0, stream>>>(src, dst, cnt, bkt, x, xh,
                                       Wn0, Ws0, Wn1, Ws1, Wn2, Ws2, wfrag);

    const int layer_blocks = (NN + 63) / 64;    // 1563
    _Float16* wf0 = wfrag;
    _Float16* wf1 = wfrag + 4 * FRAG_ELEMS;
    _Float16* wf2 = wfrag + 8 * FRAG_ELEMS;

    // layer 0: xh -> hA (relu) ; layer 1: hA -> hB (relu) ; layer 2: hB -> emb fp32
    k_layer<<<layer_blocks, 256, 0, stream>>>(xh, cnt, bkt, wf0, b0, hA, nullptr);
    k_layer<<<layer_blocks, 256, 0, stream>>>(hA, cnt, bkt, wf1, b1, hB, nullptr);
    k_layer<<<layer_blocks, 256, 0, stream>>>(hB, cnt, bkt, wf2, b2, nullptr, emb_out);

    // fc + log_softmax
    k_fc<<<NN / 16, 256, 0, stream>>>(emb_out, Wfc, bfc, lsm_out);
}

// Round 12
// 500.335 us; speedup vs baseline: 1.0633x; 1.0633x over previous
//
#include <hip/hip_runtime.h>
#include <hip/hip_fp16.h>

#define NN 100000
#define NE 1600000
#define DD 128
#define CAP 48           // bucket capacity; max in-degree ~40
#define FRAG_ELEMS 16384 // one 128x128 matrix in fragment order

#define NRNG 8           // dst ranges == XCD count
#define RNODES 12500     // NN / NRNG
#define EPT 8            // edges per thread in fill
#define FILL_T (NE / EPT)                 // 200000 threads per range pass
#define FILL_BPR ((FILL_T + 255) / 256)   // 782 blocks per range
#define FILL_B (NRNG * FILL_BPR)          // 6256 fill blocks (placed FIRST: rng = b&7)
#define XCAST_B ((NN * DD / 8) / 256)     // 6250 xcast blocks
#define PREP_B (FILL_B + XCAST_B + 384)   // + 384 wprep blocks = 12890

typedef __attribute__((ext_vector_type(8))) _Float16 half8;
typedef __attribute__((ext_vector_type(4))) float f32x4;

// ---------------- fused prep: fill | xcast | wprep in one dispatch ----------------
// Mutually independent; xcast (~13us) and wprep (~5us) hide under fill's ~74us.
// Fill blocks first so rng = blockIdx&7 keeps the r3 XCD mapping. cnt memset'd.
// r11 confirmed: k_prep never entered top-5 (<111us) -> fusion is sound.
__global__ __launch_bounds__(256) void k_prep(
    const int* __restrict__ src, const int* __restrict__ dst,
    int* __restrict__ cnt, int* __restrict__ bkt,
    const float* __restrict__ x, _Float16* __restrict__ xh,
    const float* __restrict__ W0, const float* __restrict__ W1,
    const float* __restrict__ W2, const float* __restrict__ W3,
    const float* __restrict__ W4, const float* __restrict__ W5,
    _Float16* __restrict__ wfrag) {

    int b = blockIdx.x;
    int tid = threadIdx.x;

    if (b < FILL_B) {
        // ---- bucket fill (r3 config, best measured over 5 scatter variants) ----
        int rng = b & (NRNG - 1);
        int t = (b >> 3) * 256 + tid;
        if (t >= FILL_T) return;
        int lo = rng * RNODES;
        const int4* d4 = (const int4*)dst;
        const int4* s4 = (const int4*)src;
        int4 d0 = d4[t * 2];
        int4 d1 = d4[t * 2 + 1];
        int4 s0 = s4[t * 2];
        int4 s1 = s4[t * 2 + 1];
        int dd[8] = { d0.x, d0.y, d0.z, d0.w, d1.x, d1.y, d1.z, d1.w };
        int ss[8] = { s0.x, s0.y, s0.z, s0.w, s1.x, s1.y, s1.z, s1.w };
#pragma unroll
        for (int k = 0; k < 8; ++k) {
            int d = dd[k];
            unsigned rel = (unsigned)(d - lo);
            if (rel < (unsigned)RNODES) {
                int p = atomicAdd(&cnt[d], 1);
                if (p < CAP) bkt[(size_t)d * CAP + p] = ss[k];
            }
        }
    } else if (b < FILL_B + XCAST_B) {
        // ---- cast x fp32 -> f16 ----
        int t = (b - FILL_B) * 256 + tid;
        const float* p = x + (size_t)t * 8;
        float4 v0 = *(const float4*)p;
        float4 v1 = *(const float4*)(p + 4);
        half8 o = { (_Float16)v0.x, (_Float16)v0.y, (_Float16)v0.z, (_Float16)v0.w,
                    (_Float16)v1.x, (_Float16)v1.y, (_Float16)v1.z, (_Float16)v1.w };
        *(half8*)(xh + (size_t)t * 8) = o;
    } else {
        // ---- weight prep: transpose + f16 hi/lo split into MFMA B-frag order ----
        int wb = b - FILL_B - XCAST_B;               // 0..383
        int mat = wb >> 6;
        int e = (wb & 63) * 256 + tid;               // 0..16383
        const float* W = (mat == 0) ? W0 : (mat == 1) ? W1 : (mat == 2) ? W2
                       : (mat == 3) ? W3 : (mat == 4) ? W4 : W5;
        int j = e & 7;
        int lane = (e >> 3) & 63;
        int ct = (e >> 9) & 7;
        int kt = e >> 12;
        int k = kt * 32 + (lane >> 4) * 8 + j;
        int n = ct * 16 + (lane & 15);
        float v = W[k * 128 + n];
        _Float16 hi = (_Float16)v;
        _Float16 lo = (_Float16)(v - (float)hi);
        _Float16* mb = wfrag + (size_t)mat * 2 * FRAG_ELEMS;
        mb[e] = hi;
        mb[FRAG_ELEMS + e] = lo;
    }
}

// ---------------- gather-aggregate (f16 rows): mean[n] = sum h[bkt]/max(deg,1) ----------------
// one wave per node; quarter q = lane>>4 owns edge (i+q); lane covers 8 f16.
// r11 lesson: this kernel NEEDS its 100K-wave TLP — fusing into 1563 fat
// blocks collapsed L2 gather reuse (FETCH 64->191 MB) and occupancy (33%).
__global__ __launch_bounds__(256) void k_agg(const _Float16* __restrict__ h,
                                             const int* __restrict__ cnt,
                                             const int* __restrict__ bkt,
                                             _Float16* __restrict__ mean) {
    int node = blockIdx.x * 4 + (threadIdx.x >> 6);
    if (node >= NN) return;
    int lane = threadIdx.x & 63;
    int q = lane >> 4;
    int col = (lane & 15) * 8;
    int deg = cnt[node];
    int n = deg > CAP ? CAP : deg;
    const int* b = bkt + (size_t)node * CAP;
    float a[8] = {};
    int i = 0;
    for (; i + 16 <= n; i += 16) {
        int s0 = b[i + q];
        int s1 = b[i + 4 + q];
        int s2 = b[i + 8 + q];
        int s3 = b[i + 12 + q];
        half8 v0 = *(const half8*)(h + (size_t)s0 * DD + col);
        half8 v1 = *(const half8*)(h + (size_t)s1 * DD + col);
        half8 v2 = *(const half8*)(h + (size_t)s2 * DD + col);
        half8 v3 = *(const half8*)(h + (size_t)s3 * DD + col);
#pragma unroll
        for (int j = 0; j < 8; ++j)
            a[j] += ((float)v0[j] + (float)v1[j]) + ((float)v2[j] + (float)v3[j]);
    }
    if (i + 8 <= n) {
        int s0 = b[i + q];
        int s1 = b[i + 4 + q];
        half8 v0 = *(const half8*)(h + (size_t)s0 * DD + col);
        half8 v1 = *(const half8*)(h + (size_t)s1 * DD + col);
#pragma unroll
        for (int j = 0; j < 8; ++j) a[j] += (float)v0[j] + (float)v1[j];
        i += 8;
    }
    if (i + 4 <= n) {
        int s0 = b[i + q];
        half8 v0 = *(const half8*)(h + (size_t)s0 * DD + col);
#pragma unroll
        for (int j = 0; j < 8; ++j) a[j] += (float)v0[j];
        i += 4;
    }
    if (i + q < n) {
        int s = b[i + q];
        half8 v = *(const half8*)(h + (size_t)s * DD + col);
#pragma unroll
        for (int j = 0; j < 8; ++j) a[j] += (float)v[j];
    }
    // reduce the 4 quarters
#pragma unroll
    for (int j = 0; j < 8; ++j) {
        a[j] += __shfl_xor(a[j], 16);
        a[j] += __shfl_xor(a[j], 32);
    }
    if (q == 0) {
        float di = 1.0f / (float)(deg > 1 ? deg : 1);
        half8 o;
#pragma unroll
        for (int j = 0; j < 8; ++j) o[j] = (_Float16)(a[j] * di);
        *(half8*)(mean + (size_t)node * DD + col) = o;
    }
}

// ---------------- fused transform: out = act( mean@Wn + h@Ws + b ) ----------------
// LDS-staged weights (r7) + register prefetch (r9). Final layer (outf mode)
// additionally fuses fc(128->16)+log_softmax in the epilogue: the wave already
// holds each emb row's 128 cols across its 16-lane row group (col = ct*16+m16,
// row = kg*4+i), so fc = 512 FMA/lane + 4-step butterfly over the row group.
// Deletes the k_fc launch + 51.2 MB emb re-read. Bias added AFTER the
// butterfly (it would be 16x-summed before). Output extraction uses a
// compile-time cndmask chain (no runtime register indexing -> no scratch).
__global__ __launch_bounds__(256) void k_gemm(
    const _Float16* __restrict__ meanp, const _Float16* __restrict__ hin,
    const _Float16* __restrict__ wf,   // [WnHi|WnLo|WsHi|WsLo] x 16384
    const float* __restrict__ bias,
    _Float16* __restrict__ outh, float* __restrict__ outf,
    const float* __restrict__ Wfc, const float* __restrict__ bfc,
    float* __restrict__ lsm) {

    __shared__ _Float16 sw[2][4096];   // hi/lo chunk for one kt: 16 KB

    int t = threadIdx.x;
    int wave = t >> 6;
    int lane = t & 63;
    int m16 = lane & 15;
    int kg = lane >> 4;
    int rowA = blockIdx.x * 64 + wave * 16 + m16;
    if (rowA >= NN) rowA = NN - 1;       // clamp (store is guarded)

    // one-time A prefetch: afrag[s][kt]
    half8 afrag[2][4];
    {
        const _Float16* Am = meanp + (size_t)rowA * DD + kg * 8;
        const _Float16* Ah = hin  + (size_t)rowA * DD + kg * 8;
#pragma unroll
        for (int kt = 0; kt < 4; ++kt) {
            afrag[0][kt] = *(const half8*)(Am + kt * 32);
            afrag[1][kt] = *(const half8*)(Ah + kt * 32);
        }
    }

    // prefetch chunk 0 (s=0, kt=0) weight data into registers
    half8 ph0, ph1, pl0, pl1;
    {
        const half8* gh = (const half8*)(wf);                 // s=0 hi, kt=0
        const half8* gl = (const half8*)(wf + FRAG_ELEMS);    // s=0 lo, kt=0
        ph0 = gh[t]; ph1 = gh[t + 256];
        pl0 = gl[t]; pl1 = gl[t + 256];
    }

    f32x4 acc[8] = {};

#pragma unroll
    for (int idx = 0; idx < 8; ++idx) {
        int s = idx >> 2;
        int kt = idx & 3;
        __syncthreads();           // previous chunk's LDS reads done
        {
            half8* dsth = (half8*)sw[0];
            half8* dstl = (half8*)sw[1];
            dsth[t]       = ph0;
            dsth[t + 256] = ph1;
            dstl[t]       = pl0;
            dstl[t + 256] = pl1;
        }
        if (idx < 7) {             // issue next chunk's loads; latency hides under MFMA
            int s2 = (idx + 1) >> 2;
            int kt2 = (idx + 1) & 3;
            const half8* gh = (const half8*)(wf + s2 * 2 * FRAG_ELEMS + kt2 * 4096);
            const half8* gl = (const half8*)(wf + s2 * 2 * FRAG_ELEMS + FRAG_ELEMS + kt2 * 4096);
            ph0 = gh[t]; ph1 = gh[t + 256];
            pl0 = gl[t]; pl1 = gl[t + 256];
        }
        __syncthreads();
        half8 a = afrag[s][kt];
#pragma unroll
        for (int ct = 0; ct < 8; ++ct) {
            half8 bh = *(const half8*)(sw[0] + (ct * 64 + lane) * 8);
            half8 bl = *(const half8*)(sw[1] + (ct * 64 + lane) * 8);
            acc[ct] = __builtin_amdgcn_mfma_f32_16x16x32_f16(a, bh, acc[ct], 0, 0, 0);
            acc[ct] = __builtin_amdgcn_mfma_f32_16x16x32_f16(a, bl, acc[ct], 0, 0, 0);
        }
    }

    // epilogue: C layout col=lane&15, row=(lane>>4)*4+reg
    int rbase = blockIdx.x * 64 + wave * 16 + kg * 4;
    if (outh) {
#pragma unroll
        for (int ct = 0; ct < 8; ++ct) {
            int col = ct * 16 + m16;
            float bv = bias[col];
#pragma unroll
            for (int i = 0; i < 4; ++i) {
                int r = rbase + i;
                if (r < NN)
                    outh[(size_t)r * DD + col] = (_Float16)fmaxf(acc[ct][i] + bv, 0.0f);
            }
        }
    } else {
        // emb write + fused fc/log_softmax
        float embv[8][4];
#pragma unroll
        for (int ct = 0; ct < 8; ++ct) {
            int col = ct * 16 + m16;
            float bv = bias[col];
#pragma unroll
            for (int i = 0; i < 4; ++i) {
                embv[ct][i] = acc[ct][i] + bv;
                int r = rbase + i;
                if (r < NN)
                    outf[(size_t)r * DD + col] = embv[ct][i];
            }
        }
        __syncthreads();                 // all MFMA reads of sw done; reuse as Wfc
        float* swf = (float*)sw;         // [128][16] fp32 = 8 KB
        *(float4*)(swf + t * 8)     = *(const float4*)(Wfc + t * 8);
        *(float4*)(swf + t * 8 + 4) = *(const float4*)(Wfc + t * 8 + 4);
        __syncthreads();
#pragma unroll
        for (int i = 0; i < 4; ++i) {
            float p[16];
#pragma unroll
            for (int o = 0; o < 16; ++o) p[o] = 0.0f;
#pragma unroll
            for (int ct = 0; ct < 8; ++ct) {
                const float* wr = swf + (ct * 16 + m16) * 16;
                float4 w0 = *(const float4*)(wr);
                float4 w1 = *(const float4*)(wr + 4);
                float4 w2 = *(const float4*)(wr + 8);
                float4 w3 = *(const float4*)(wr + 12);
                float e = embv[ct][i];
                p[0]  += e * w0.x; p[1]  += e * w0.y; p[2]  += e * w0.z; p[3]  += e * w0.w;
                p[4]  += e * w1.x; p[5]  += e * w1.y; p[6]  += e * w1.z; p[7]  += e * w1.w;
                p[8]  += e * w2.x; p[9]  += e * w2.y; p[10] += e * w2.z; p[11] += e * w2.w;
                p[12] += e * w3.x; p[13] += e * w3.y; p[14] += e * w3.z; p[15] += e * w3.w;
            }
            // butterfly over the 16-lane row group (xor bits < 16 stay in-group)
#pragma unroll
            for (int d = 1; d < 16; d <<= 1) {
#pragma unroll
                for (int o = 0; o < 16; ++o) p[o] += __shfl_xor(p[o], d);
            }
#pragma unroll
            for (int o = 0; o < 16; ++o) p[o] += bfc[o];
            float mx = p[0];
#pragma unroll
            for (int o = 1; o < 16; ++o) mx = fmaxf(mx, p[o]);
            float se = 0.0f;
#pragma unroll
            for (int o = 0; o < 16; ++o) se += expf(p[o] - mx);
            float lse = mx + logf(se);
            float val = p[0];
#pragma unroll
            for (int o = 1; o < 16; ++o) val = (m16 == o) ? p[o] : val;
            int r = rbase + i;
            if (r < NN)
                lsm[(size_t)r * 16 + m16] = val - lse;
        }
    }
}

extern "C" void kernel_launch(void* const* d_in, const int* in_sizes, int n_in,
                              void* d_out, int out_size, void* d_ws, size_t ws_size,
                              hipStream_t stream) {
    const float* x   = (const float*)d_in[0];
    const int*   ei  = (const int*)d_in[1];
    const float* Wn0 = (const float*)d_in[2];
    const float* Ws0 = (const float*)d_in[3];
    const float* b0  = (const float*)d_in[4];
    const float* Wn1 = (const float*)d_in[5];
    const float* Ws1 = (const float*)d_in[6];
    const float* b1  = (const float*)d_in[7];
    const float* Wn2 = (const float*)d_in[8];
    const float* Ws2 = (const float*)d_in[9];
    const float* b2  = (const float*)d_in[10];
    const float* Wfc = (const float*)d_in[11];
    const float* bfc = (const float*)d_in[12];

    const int* src = ei;
    const int* dst = ei + NE;

    float* emb_out = (float*)d_out;
    float* lsm_out = emb_out + (size_t)NN * 128;

    char* ws = (char*)d_ws;
    _Float16* xh    = (_Float16*)(ws);                   //  25,600,000 B
    _Float16* hA    = (_Float16*)(ws + 25600000);        //  25,600,000 B
    _Float16* hB    = (_Float16*)(ws + 51200000);        //  25,600,000 B
    _Float16* mean  = (_Float16*)(ws + 76800000);        //  25,600,000 B
    int*      cnt   = (int*)     (ws + 102400000);       //     400,000 B
    int*      bkt   = (int*)     (ws + 102800000);       //  19,200,000 B (CAP=48)
    _Float16* wfrag = (_Float16*)(ws + 122000000);       //     393,216 B

    // ---- fused prep: memset cnt, then fill | xcast | wprep concurrently ----
    hipMemsetAsync(cnt, 0, NN * sizeof(int), stream);
    k_prep<<<PREP_B, 256, 0, stream>>>(src, dst, cnt, bkt, x, xh,
                                       Wn0, Ws0, Wn1, Ws1, Wn2, Ws2, wfrag);

    const int agg_blocks  = (NN + 3) / 4;       // 25000
    const int gemm_blocks = (NN + 63) / 64;     // 1563
    _Float16* wf0 = wfrag;
    _Float16* wf1 = wfrag + 4 * FRAG_ELEMS;
    _Float16* wf2 = wfrag + 8 * FRAG_ELEMS;

    // layer 0: xh -> hA (relu)
    k_agg<<<agg_blocks, 256, 0, stream>>>(xh, cnt, bkt, mean);
    k_gemm<<<gemm_blocks, 256, 0, stream>>>(mean, xh, wf0, b0, hA, nullptr,
                                            nullptr, nullptr, nullptr);

    // layer 1: hA -> hB (relu)
    k_agg<<<agg_blocks, 256, 0, stream>>>(hA, cnt, bkt, mean);
    k_gemm<<<gemm_blocks, 256, 0, stream>>>(mean, hA, wf1, b1, hB, nullptr,
                                            nullptr, nullptr, nullptr);

    // layer 2: hB -> emb fp32 + fused fc/log_softmax
    k_agg<<<agg_blocks, 256, 0, stream>>>(hB, cnt, bkt, mean);
    k_gemm<<<gemm_blocks, 256, 0, stream>>>(mean, hB, wf2, b2, nullptr, emb_out,
                                            Wfc, bfc, lsm_out);
}

// Round 13
// 483.067 us; speedup vs baseline: 1.1013x; 1.0357x over previous
//
#include <hip/hip_runtime.h>
#include <hip/hip_fp16.h>

#define NN 100000
#define NE 1600000
#define DD 128
#define CAP 48           // bucket capacity; max in-degree ~40
#define FRAG_ELEMS 16384 // one 128x128 matrix in fragment order

#define NRNG 8           // dst ranges == XCD count
#define RNODES 12500     // NN / NRNG
#define EPT 8            // edges per thread in fill
#define FILL_T (NE / EPT)                 // 200000 threads per range pass
#define FILL_BPR ((FILL_T + 255) / 256)   // 782 blocks per range
#define FILL_B (NRNG * FILL_BPR)          // 6256 fill blocks (placed FIRST: rng = b&7)
#define XCAST_B ((NN * DD / 8) / 256)     // 6250 xcast blocks
#define PREP_B (FILL_B + XCAST_B + 384)   // + 384 wprep blocks = 12890

typedef __attribute__((ext_vector_type(8))) _Float16 half8;
typedef __attribute__((ext_vector_type(4))) float f32x4;

// ---------------- fused prep: fill | xcast | wprep in one dispatch ----------------
// Mutually independent; xcast (~13us) and wprep (~5us) hide under fill's ~74us.
// Fill blocks first so rng = blockIdx&7 keeps the r3 XCD mapping. cnt memset'd.
// r11/r12 confirmed: k_prep never entered top-5 -> fusion is sound.
__global__ __launch_bounds__(256) void k_prep(
    const int* __restrict__ src, const int* __restrict__ dst,
    int* __restrict__ cnt, int* __restrict__ bkt,
    const float* __restrict__ x, _Float16* __restrict__ xh,
    const float* __restrict__ W0, const float* __restrict__ W1,
    const float* __restrict__ W2, const float* __restrict__ W3,
    const float* __restrict__ W4, const float* __restrict__ W5,
    _Float16* __restrict__ wfrag) {

    int b = blockIdx.x;
    int tid = threadIdx.x;

    if (b < FILL_B) {
        // ---- bucket fill (r3 config, best measured over 5 scatter variants) ----
        int rng = b & (NRNG - 1);
        int t = (b >> 3) * 256 + tid;
        if (t >= FILL_T) return;
        int lo = rng * RNODES;
        const int4* d4 = (const int4*)dst;
        const int4* s4 = (const int4*)src;
        int4 d0 = d4[t * 2];
        int4 d1 = d4[t * 2 + 1];
        int4 s0 = s4[t * 2];
        int4 s1 = s4[t * 2 + 1];
        int dd[8] = { d0.x, d0.y, d0.z, d0.w, d1.x, d1.y, d1.z, d1.w };
        int ss[8] = { s0.x, s0.y, s0.z, s0.w, s1.x, s1.y, s1.z, s1.w };
#pragma unroll
        for (int k = 0; k < 8; ++k) {
            int d = dd[k];
            unsigned rel = (unsigned)(d - lo);
            if (rel < (unsigned)RNODES) {
                int p = atomicAdd(&cnt[d], 1);
                if (p < CAP) bkt[(size_t)d * CAP + p] = ss[k];
            }
        }
    } else if (b < FILL_B + XCAST_B) {
        // ---- cast x fp32 -> f16 ----
        int t = (b - FILL_B) * 256 + tid;
        const float* p = x + (size_t)t * 8;
        float4 v0 = *(const float4*)p;
        float4 v1 = *(const float4*)(p + 4);
        half8 o = { (_Float16)v0.x, (_Float16)v0.y, (_Float16)v0.z, (_Float16)v0.w,
                    (_Float16)v1.x, (_Float16)v1.y, (_Float16)v1.z, (_Float16)v1.w };
        *(half8*)(xh + (size_t)t * 8) = o;
    } else {
        // ---- weight prep: transpose + f16 hi/lo split into MFMA B-frag order ----
        int wb = b - FILL_B - XCAST_B;               // 0..383
        int mat = wb >> 6;
        int e = (wb & 63) * 256 + tid;               // 0..16383
        const float* W = (mat == 0) ? W0 : (mat == 1) ? W1 : (mat == 2) ? W2
                       : (mat == 3) ? W3 : (mat == 4) ? W4 : W5;
        int j = e & 7;
        int lane = (e >> 3) & 63;
        int ct = (e >> 9) & 7;
        int kt = e >> 12;
        int k = kt * 32 + (lane >> 4) * 8 + j;
        int n = ct * 16 + (lane & 15);
        float v = W[k * 128 + n];
        _Float16 hi = (_Float16)v;
        _Float16 lo = (_Float16)(v - (float)hi);
        _Float16* mb = wfrag + (size_t)mat * 2 * FRAG_ELEMS;
        mb[e] = hi;
        mb[FRAG_ELEMS + e] = lo;
    }
}

// ---------------- gather-aggregate (f16 rows): mean[n] = sum h[bkt]/max(deg,1) ----------------
// one wave per node; quarter q = lane>>4 owns edge (i+q); lane covers 8 f16.
// r11 lesson: this kernel NEEDS its 100K-wave TLP — fusing into 1563 fat
// blocks collapsed L2 gather reuse (FETCH 64->191 MB) and occupancy (33%).
__global__ __launch_bounds__(256) void k_agg(const _Float16* __restrict__ h,
                                             const int* __restrict__ cnt,
                                             const int* __restrict__ bkt,
                                             _Float16* __restrict__ mean) {
    int node = blockIdx.x * 4 + (threadIdx.x >> 6);
    if (node >= NN) return;
    int lane = threadIdx.x & 63;
    int q = lane >> 4;
    int col = (lane & 15) * 8;
    int deg = cnt[node];
    int n = deg > CAP ? CAP : deg;
    const int* b = bkt + (size_t)node * CAP;
    float a[8] = {};
    int i = 0;
    for (; i + 16 <= n; i += 16) {
        int s0 = b[i + q];
        int s1 = b[i + 4 + q];
        int s2 = b[i + 8 + q];
        int s3 = b[i + 12 + q];
        half8 v0 = *(const half8*)(h + (size_t)s0 * DD + col);
        half8 v1 = *(const half8*)(h + (size_t)s1 * DD + col);
        half8 v2 = *(const half8*)(h + (size_t)s2 * DD + col);
        half8 v3 = *(const half8*)(h + (size_t)s3 * DD + col);
#pragma unroll
        for (int j = 0; j < 8; ++j)
            a[j] += ((float)v0[j] + (float)v1[j]) + ((float)v2[j] + (float)v3[j]);
    }
    if (i + 8 <= n) {
        int s0 = b[i + q];
        int s1 = b[i + 4 + q];
        half8 v0 = *(const half8*)(h + (size_t)s0 * DD + col);
        half8 v1 = *(const half8*)(h + (size_t)s1 * DD + col);
#pragma unroll
        for (int j = 0; j < 8; ++j) a[j] += (float)v0[j] + (float)v1[j];
        i += 8;
    }
    if (i + 4 <= n) {
        int s0 = b[i + q];
        half8 v0 = *(const half8*)(h + (size_t)s0 * DD + col);
#pragma unroll
        for (int j = 0; j < 8; ++j) a[j] += (float)v0[j];
        i += 4;
    }
    if (i + q < n) {
        int s = b[i + q];
        half8 v = *(const half8*)(h + (size_t)s * DD + col);
#pragma unroll
        for (int j = 0; j < 8; ++j) a[j] += (float)v[j];
    }
    // reduce the 4 quarters
#pragma unroll
    for (int j = 0; j < 8; ++j) {
        a[j] += __shfl_xor(a[j], 16);
        a[j] += __shfl_xor(a[j], 32);
    }
    if (q == 0) {
        float di = 1.0f / (float)(deg > 1 ? deg : 1);
        half8 o;
#pragma unroll
        for (int j = 0; j < 8; ++j) o[j] = (_Float16)(a[j] * di);
        *(half8*)(mean + (size_t)node * DD + col) = o;
    }
}

// ---------------- fused transform: out = act( mean@Wn + h@Ws + b ) ----------------
// A is f16 (stored), B is f16 hi+lo (fp32-grade weights), fp32 accumulate.
// LDS-staged weights (r7, -42us) + register prefetch hoisting the global
// weight load out of the barrier pair (r9). r12 lesson: do NOT fuse fc here —
// the epilogue went 8-way LDS-bank-conflicted (9.7M cycles), added 256 shfl +
// 64 expf per thread, and the runtime branch bloated ALL layers to 80 VGPR /
// 28% occupancy. Separate k_fc is 10us and fine.
__global__ __launch_bounds__(256) void k_gemm(
    const _Float16* __restrict__ meanp, const _Float16* __restrict__ hin,
    const _Float16* __restrict__ wf,   // [WnHi|WnLo|WsHi|WsLo] x 16384
    const float* __restrict__ bias,
    _Float16* __restrict__ outh, float* __restrict__ outf) {

    __shared__ _Float16 sw[2][4096];   // hi/lo chunk for one kt: 16 KB

    int t = threadIdx.x;
    int wave = t >> 6;
    int lane = t & 63;
    int m16 = lane & 15;
    int kg = lane >> 4;
    int rowA = blockIdx.x * 64 + wave * 16 + m16;
    if (rowA >= NN) rowA = NN - 1;       // clamp (store is guarded)

    // one-time A prefetch: afrag[s][kt]
    half8 afrag[2][4];
    {
        const _Float16* Am = meanp + (size_t)rowA * DD + kg * 8;
        const _Float16* Ah = hin  + (size_t)rowA * DD + kg * 8;
#pragma unroll
        for (int kt = 0; kt < 4; ++kt) {
            afrag[0][kt] = *(const half8*)(Am + kt * 32);
            afrag[1][kt] = *(const half8*)(Ah + kt * 32);
        }
    }

    // prefetch chunk 0 (s=0, kt=0) weight data into registers
    half8 ph0, ph1, pl0, pl1;
    {
        const half8* gh = (const half8*)(wf);                 // s=0 hi, kt=0
        const half8* gl = (const half8*)(wf + FRAG_ELEMS);    // s=0 lo, kt=0
        ph0 = gh[t]; ph1 = gh[t + 256];
        pl0 = gl[t]; pl1 = gl[t + 256];
    }

    f32x4 acc[8] = {};

#pragma unroll
    for (int idx = 0; idx < 8; ++idx) {
        int s = idx >> 2;
        int kt = idx & 3;
        __syncthreads();           // previous chunk's LDS reads done
        {
            half8* dsth = (half8*)sw[0];
            half8* dstl = (half8*)sw[1];
            dsth[t]       = ph0;
            dsth[t + 256] = ph1;
            dstl[t]       = pl0;
            dstl[t + 256] = pl1;
        }
        if (idx < 7) {             // issue next chunk's loads; latency hides under MFMA
            int s2 = (idx + 1) >> 2;
            int kt2 = (idx + 1) & 3;
            const half8* gh = (const half8*)(wf + s2 * 2 * FRAG_ELEMS + kt2 * 4096);
            const half8* gl = (const half8*)(wf + s2 * 2 * FRAG_ELEMS + FRAG_ELEMS + kt2 * 4096);
            ph0 = gh[t]; ph1 = gh[t + 256];
            pl0 = gl[t]; pl1 = gl[t + 256];
        }
        __syncthreads();
        half8 a = afrag[s][kt];
#pragma unroll
        for (int ct = 0; ct < 8; ++ct) {
            half8 bh = *(const half8*)(sw[0] + (ct * 64 + lane) * 8);
            half8 bl = *(const half8*)(sw[1] + (ct * 64 + lane) * 8);
            acc[ct] = __builtin_amdgcn_mfma_f32_16x16x32_f16(a, bh, acc[ct], 0, 0, 0);
            acc[ct] = __builtin_amdgcn_mfma_f32_16x16x32_f16(a, bl, acc[ct], 0, 0, 0);
        }
    }

    // epilogue: C layout col=lane&15, row=(lane>>4)*4+reg
    int rbase = blockIdx.x * 64 + wave * 16 + kg * 4;
    if (outh) {
#pragma unroll
        for (int ct = 0; ct < 8; ++ct) {
            int col = ct * 16 + m16;
            float bv = bias[col];
#pragma unroll
            for (int i = 0; i < 4; ++i) {
                int r = rbase + i;
                if (r < NN)
                    outh[(size_t)r * DD + col] = (_Float16)fmaxf(acc[ct][i] + bv, 0.0f);
            }
        }
    } else {
#pragma unroll
        for (int ct = 0; ct < 8; ++ct) {
            int col = ct * 16 + m16;
            float bv = bias[col];
#pragma unroll
            for (int i = 0; i < 4; ++i) {
                int r = rbase + i;
                if (r < NN)
                    outf[(size_t)r * DD + col] = acc[ct][i] + bv;
            }
        }
    }
}

// ---------------- fc (128->16) + log_softmax (fp32) ----------------
__global__ __launch_bounds__(256) void k_fc(const float* __restrict__ emb,
                                            const float* __restrict__ Wfc,
                                            const float* __restrict__ bfc,
                                            float* __restrict__ out) {
    __shared__ float se[16 * 128];
    __shared__ float swt[128 * 16];
    int t = threadIdx.x;
    int nb = blockIdx.x * 16;
    int idx = t * 8;
    *(float4*)(se + idx)      = *(const float4*)(emb + (size_t)nb * 128 + idx);
    *(float4*)(se + idx + 4)  = *(const float4*)(emb + (size_t)nb * 128 + idx + 4);
    *(float4*)(swt + idx)     = *(const float4*)(Wfc + idx);
    *(float4*)(swt + idx + 4) = *(const float4*)(Wfc + idx + 4);
    __syncthreads();

    int nl = t >> 4;
    int o = t & 15;
    float acc = bfc[o];
    const float* er = se + nl * 128;
#pragma unroll 8
    for (int k = 0; k < 128; ++k)
        acc += er[k] * swt[k * 16 + o];

    float m = acc;
#pragma unroll
    for (int d = 1; d < 16; d <<= 1) m = fmaxf(m, __shfl_xor(m, d, 16));
    float e = expf(acc - m);
    float ssum = e;
#pragma unroll
    for (int d = 1; d < 16; d <<= 1) ssum += __shfl_xor(ssum, d, 16);
    out[(size_t)(nb + nl) * 16 + o] = (acc - m) - logf(ssum);
}

extern "C" void kernel_launch(void* const* d_in, const int* in_sizes, int n_in,
                              void* d_out, int out_size, void* d_ws, size_t ws_size,
                              hipStream_t stream) {
    const float* x   = (const float*)d_in[0];
    const int*   ei  = (const int*)d_in[1];
    const float* Wn0 = (const float*)d_in[2];
    const float* Ws0 = (const float*)d_in[3];
    const float* b0  = (const float*)d_in[4];
    const float* Wn1 = (const float*)d_in[5];
    const float* Ws1 = (const float*)d_in[6];
    const float* b1  = (const float*)d_in[7];
    const float* Wn2 = (const float*)d_in[8];
    const float* Ws2 = (const float*)d_in[9];
    const float* b2  = (const float*)d_in[10];
    const float* Wfc = (const float*)d_in[11];
    const float* bfc = (const float*)d_in[12];

    const int* src = ei;
    const int* dst = ei + NE;

    float* emb_out = (float*)d_out;
    float* lsm_out = emb_out + (size_t)NN * 128;

    char* ws = (char*)d_ws;
    _Float16* xh    = (_Float16*)(ws);                   //  25,600,000 B
    _Float16* hA    = (_Float16*)(ws + 25600000);        //  25,600,000 B
    _Float16* hB    = (_Float16*)(ws + 51200000);        //  25,600,000 B
    _Float16* mean  = (_Float16*)(ws + 76800000);        //  25,600,000 B
    int*      cnt   = (int*)     (ws + 102400000);       //     400,000 B
    int*      bkt   = (int*)     (ws + 102800000);       //  19,200,000 B (CAP=48)
    _Float16* wfrag = (_Float16*)(ws + 122000000);       //     393,216 B

    // ---- fused prep: memset cnt, then fill | xcast | wprep concurrently ----
    hipMemsetAsync(cnt, 0, NN * sizeof(int), stream);
    k_prep<<<PREP_B, 256, 0, stream>>>(src, dst, cnt, bkt, x, xh,
                                       Wn0, Ws0, Wn1, Ws1, Wn2, Ws2, wfrag);

    const int agg_blocks  = (NN + 3) / 4;       // 25000
    const int gemm_blocks = (NN + 63) / 64;     // 1563
    _Float16* wf0 = wfrag;
    _Float16* wf1 = wfrag + 4 * FRAG_ELEMS;
    _Float16* wf2 = wfrag + 8 * FRAG_ELEMS;

    // layer 0: xh -> hA (relu)
    k_agg<<<agg_blocks, 256, 0, stream>>>(xh, cnt, bkt, mean);
    k_gemm<<<gemm_blocks, 256, 0, stream>>>(mean, xh, wf0, b0, hA, nullptr);

    // layer 1: hA -> hB (relu)
    k_agg<<<agg_blocks, 256, 0, stream>>>(hA, cnt, bkt, mean);
    k_gemm<<<gemm_blocks, 256, 0, stream>>>(mean, hA, wf1, b1, hB, nullptr);

    // layer 2: hB -> emb fp32 (no relu)
    k_agg<<<agg_blocks, 256, 0, stream>>>(hB, cnt, bkt, mean);
    k_gemm<<<gemm_blocks, 256, 0, stream>>>(mean, hB, wf2, b2, nullptr, emb_out);

    // fc + log_softmax
    k_fc<<<NN / 16, 256, 0, stream>>>(emb_out, Wfc, bfc, lsm_out);
}